// Round 9
// baseline (110.827 us; speedup 1.0000x reference)
//
#include <hip/hip_runtime.h>

// ---- problem constants ----
#define Bb 32     // batch
#define NN 1024   // H*W = K dim = output cols per channel
#define CC 128    // channels
#define KS 64     // K step per LDS stage
#define MT 128    // m-cols per block (4 waves x 32)
#define NSTEP (NN / KS)  // 16

typedef __bf16 bf16x8 __attribute__((ext_vector_type(8)));
typedef __bf16 bf16x4 __attribute__((ext_vector_type(4)));
typedef float f32x16 __attribute__((ext_vector_type(16)));
typedef float f32x4 __attribute__((ext_vector_type(4)));
typedef unsigned short u16x8 __attribute__((ext_vector_type(8)));

// ---------------------------------------------------------------------------
// Pre-pass: inputs [B, N, C] fp32 -> xbf [C, B, N] bf16. Unchanged from R1.
// ---------------------------------------------------------------------------
__global__ __launch_bounds__(256) void transpose_x(const float* __restrict__ in,
                                                   __bf16* __restrict__ xbf) {
    __shared__ float tile[64 * 132];
    const int b  = blockIdx.x >> 4;
    const int n0 = (blockIdx.x & 15) << 6;
    const int t  = threadIdx.x;

#pragma unroll
    for (int p = 0; p < 8; ++p) {
        int f     = p * 256 + t;
        int n_off = f >> 5;
        int c4    = (f & 31) << 2;
        f32x4 v = *reinterpret_cast<const f32x4*>(in + ((size_t)(b * NN + n0 + n_off) * CC + c4));
        *reinterpret_cast<f32x4*>(&tile[n_off * 132 + c4]) = v;
    }
    __syncthreads();

    const int c = t >> 1, half = t & 1;
    const size_t obase = ((size_t)c * Bb + b) * NN + n0;
#pragma unroll
    for (int q = 0; q < 4; ++q) {
        int nb = half * 32 + q * 8;
        bf16x8 o;
#pragma unroll
        for (int j = 0; j < 8; ++j) o[j] = (__bf16)tile[(nb + j) * 132 + c];
        *reinterpret_cast<bf16x8*>(xbf + obase + nb) = o;
    }
}

// ---------------------------------------------------------------------------
// Main GEMM — R8 data paths (nt W loads, block-private linear partials) with
// the load-issue point moved to the START of the MFMA phase: the next
// __syncthreads' vmcnt(0) drain is then a full phase (>=1us) after issue, so
// the 900-cycle HBM latency is covered. qA/qB: named buffers, static indexing.
// Partials now bf16 (halves part traffic; |y|<~6 so quant err ~0.03).
// ---------------------------------------------------------------------------
__global__ __launch_bounds__(256) void cwdense_part(const float* __restrict__ W,
                                                    const float* __restrict__ bias,
                                                    const __bf16* __restrict__ xbf,
                                                    __bf16* __restrict__ part) {
    __shared__ __bf16 wlds[MT * 64];  // 16 KB, row = 64 bf16 = 128 B

    const int x     = blockIdx.x;
    const int xcd   = x & 7;
    const int i     = x >> 3;
    const int c     = xcd * 16 + (i & 15);
    const int mtile = i >> 4;
    const int m0    = mtile * MT;

    const int t    = threadIdx.x;
    const int w    = t >> 6;
    const int lane = t & 63;
    const int lm   = lane & 31;
    const int lh   = lane >> 5;
    const int m_loc = w * 32 + lm;

    const float* wpanel = W + (size_t)c * NN * NN + m0;
    const __bf16* xrow  = xbf + (size_t)(c * Bb + lm) * NN;

    const int mq  = t & 31;
    const int kq2 = t >> 5;

    f32x16 acc;
#pragma unroll
    for (int r = 0; r < 16; ++r) acc[r] = 0.0f;

    f32x4 qA[8], qB[8];

    auto load_tile = [&](f32x4 (&q)[8], int k0) {
#pragma unroll
        for (int r = 0; r < 8; ++r) {
            const int kk = (kq2 * 2 + (r >> 2)) * 4 + (r & 3);
            q[r] = __builtin_nontemporal_load(reinterpret_cast<const f32x4*>(
                wpanel + (size_t)(k0 + kk) * NN + mq * 4));
        }
    };

    auto store_tile = [&](const f32x4 (&q)[8]) {
#pragma unroll
        for (int qi = 0; qi < 2; ++qi) {
            const int kkbase = (kq2 * 2 + qi) * 4;
#pragma unroll
            for (int j = 0; j < 4; ++j) {
                const int m = mq * 4 + j;
                bf16x4 o;
#pragma unroll
                for (int r = 0; r < 4; ++r) o[r] = (__bf16)q[qi * 4 + r][j];
                const int slot = (kkbase >> 3) ^ (m & 7) ^ ((m >> 3) & 7);
                *reinterpret_cast<bf16x4*>(&wlds[m * 64 + slot * 8 + (kkbase & 7)]) = o;
            }
        }
    };

    auto mfma_step = [&](int k0) {
#pragma unroll
        for (int mi = 0; mi < 4; ++mi) {
            const int kk = mi * 16 + lh * 8;
            bf16x8 a = *reinterpret_cast<const bf16x8*>(xrow + k0 + kk);
            const int slot = (kk >> 3) ^ (m_loc & 7) ^ ((m_loc >> 3) & 7);
            bf16x8 bfrag = *reinterpret_cast<const bf16x8*>(&wlds[m_loc * 64 + slot * 8]);
            acc = __builtin_amdgcn_mfma_f32_32x32x16_bf16(a, bfrag, acc, 0, 0, 0);
        }
    };

    // prologue: W(0) in flight
    load_tile(qA, 0);

#pragma unroll 1
    for (int s = 0; s < NSTEP; s += 2) {
        // even step s: consume qA
        __syncthreads();                     // drain: qA is ~1 phase old -> cheap
        store_tile(qA);
        __syncthreads();                     // nothing vm-issued since -> free drain
        load_tile(qB, (s + 1) * KS);         // issue at START of MFMA phase
        mfma_step(s * KS);

        // odd step s+1: consume qB
        __syncthreads();
        store_tile(qB);
        __syncthreads();
        if (s + 2 < NSTEP) load_tile(qA, (s + 2) * KS);
        mfma_step((s + 1) * KS);
    }

    // epilogue: bias + relu -> part[c][b][m] bf16, block-private full 64-B lines
    const int m  = m0 + m_loc;
    const float bv = bias[(size_t)c * NN + m];
    __bf16* pc = part + (size_t)c * Bb * NN;
#pragma unroll
    for (int r = 0; r < 16; ++r) {
        const int brow = (r & 3) + 8 * (r >> 2) + 4 * lh;
        float v = acc[r] + bv;
        v = v > 0.0f ? v : 0.0f;
        pc[(size_t)brow * NN + m] = (__bf16)v;
    }
}

// ---------------------------------------------------------------------------
// Permute pass: part[c][b][m] bf16 -> out[b][m][co] f32, co = 127 - c.
// Reads vectorized bf16x8 (128-B runs per c-row); writes full f32x4 lines.
// Grid 512 = b(32) x m-tile(16 of 64).
// ---------------------------------------------------------------------------
__global__ __launch_bounds__(256) void permute_out(const __bf16* __restrict__ part,
                                                   float* __restrict__ out) {
    __shared__ float st[CC * 65];  // [c][mm], pad 65
    const int b  = blockIdx.x >> 4;
    const int m0 = (blockIdx.x & 15) * 64;
    const int t  = threadIdx.x;

    {
        const int c = t >> 1, half = t & 1;
        const __bf16* src = part + ((size_t)c * Bb + b) * NN + m0 + half * 32;
#pragma unroll
        for (int q = 0; q < 4; ++q) {
            bf16x8 v = *reinterpret_cast<const bf16x8*>(src + q * 8);
#pragma unroll
            for (int j = 0; j < 8; ++j)
                st[c * 65 + half * 32 + q * 8 + j] = (float)v[j];
        }
    }
    __syncthreads();
    {
        const int co4 = (t & 31) * 4, mr = t >> 5;
#pragma unroll
        for (int jj = 0; jj < 8; ++jj) {
            const int mloc = mr + 8 * jj;
            f32x4 v;
#pragma unroll
            for (int i = 0; i < 4; ++i)
                v[i] = st[(CC - 1 - co4 - i) * 65 + mloc];
            __builtin_nontemporal_store(v, reinterpret_cast<f32x4*>(
                out + ((size_t)b * NN + m0 + mloc) * CC + co4));
        }
    }
}

// ---------------------------------------------------------------------------
// Fallback (ws too small): R1's direct-out kernel, verbatim.
// ---------------------------------------------------------------------------
template <int USE_XBF>
__global__ __launch_bounds__(256) void cwdense_direct(const float* __restrict__ W,
                                                      const float* __restrict__ bias,
                                                      const float* __restrict__ xin,
                                                      const __bf16* __restrict__ xbf,
                                                      float* __restrict__ out) {
    __shared__ __bf16 wlds[MT * 64];
    const int x = blockIdx.x, xcd = x & 7, i = x >> 3;
    const int c = xcd * 16 + (i & 15), mtile = i >> 4, m0 = mtile * MT;
    const int t = threadIdx.x, w = t >> 6, lane = t & 63;
    const int lm = lane & 31, lh = lane >> 5, m_loc = w * 32 + lm;
    const float* wpanel = W + (size_t)c * NN * NN + m0;
    const int mq = t & 31, kq2 = t >> 5;

    f32x16 acc;
#pragma unroll
    for (int r = 0; r < 16; ++r) acc[r] = 0.0f;

    for (int step = 0; step < NSTEP; ++step) {
        const int k0 = step * KS;
        f32x4 q[2][4];
#pragma unroll
        for (int qi = 0; qi < 2; ++qi)
#pragma unroll
            for (int r = 0; r < 4; ++r)
                q[qi][r] = *reinterpret_cast<const f32x4*>(
                    wpanel + (size_t)(k0 + (kq2 * 2 + qi) * 4 + r) * NN + mq * 4);
        __syncthreads();
#pragma unroll
        for (int qi = 0; qi < 2; ++qi) {
            const int kkbase = (kq2 * 2 + qi) * 4;
#pragma unroll
            for (int j = 0; j < 4; ++j) {
                const int m = mq * 4 + j;
                bf16x4 o;
#pragma unroll
                for (int r = 0; r < 4; ++r) o[r] = (__bf16)q[qi][r][j];
                const int slot = (kkbase >> 3) ^ (m & 7) ^ ((m >> 3) & 7);
                *reinterpret_cast<bf16x4*>(&wlds[m * 64 + slot * 8 + (kkbase & 7)]) = o;
            }
        }
        __syncthreads();
#pragma unroll
        for (int mi = 0; mi < 4; ++mi) {
            const int kk = mi * 16 + lh * 8;
            bf16x8 a;
            if (USE_XBF) {
                a = *reinterpret_cast<const bf16x8*>(xbf + ((size_t)(c * Bb + lm) * NN + k0 + kk));
            } else {
                u16x8 tmp;
#pragma unroll
                for (int e = 0; e < 8; ++e) {
                    float f = xin[((size_t)lm * NN + (k0 + kk + e)) * CC + c];
                    unsigned u = __builtin_bit_cast(unsigned, f);
                    u = (u + 0x7FFFu + ((u >> 16) & 1u)) >> 16;
                    tmp[e] = (unsigned short)u;
                }
                a = __builtin_bit_cast(bf16x8, tmp);
            }
            const int slot = (kk >> 3) ^ (m_loc & 7) ^ ((m_loc >> 3) & 7);
            bf16x8 bfrag = *reinterpret_cast<const bf16x8*>(&wlds[m_loc * 64 + slot * 8]);
            acc = __builtin_amdgcn_mfma_f32_32x32x16_bf16(a, bfrag, acc, 0, 0, 0);
        }
    }
    const int m = m0 + m_loc;
    const float bv = bias[(size_t)c * NN + m];
    const int co = (CC - 1) - c;
#pragma unroll
    for (int r = 0; r < 16; ++r) {
        const int brow = (r & 3) + 8 * (r >> 2) + 4 * lh;
        float v = acc[r] + bv;
        v = v > 0.0f ? v : 0.0f;
        out[(size_t)brow * (NN * CC) + (size_t)m * CC + co] = v;
    }
}

extern "C" void kernel_launch(void* const* d_in, const int* in_sizes, int n_in,
                              void* d_out, int out_size, void* d_ws, size_t ws_size,
                              hipStream_t stream) {
    const float* xinp = (const float*)d_in[0];
    const float* W    = (const float*)d_in[1];
    const float* bias = (const float*)d_in[2];
    float* out        = (float*)d_out;

    const size_t part_bytes = (size_t)CC * Bb * NN * sizeof(__bf16);  // 8 MB
    const size_t xbf_bytes  = (size_t)CC * Bb * NN * sizeof(__bf16);  // 8 MB

    if (ws_size >= part_bytes + xbf_bytes) {
        __bf16* part = (__bf16*)d_ws;
        __bf16* xbf  = (__bf16*)((char*)d_ws + part_bytes);
        transpose_x<<<512, 256, 0, stream>>>(xinp, xbf);
        cwdense_part<<<1024, 256, 0, stream>>>(W, bias, xbf, part);
        permute_out<<<512, 256, 0, stream>>>(part, out);
    } else if (ws_size >= xbf_bytes) {
        __bf16* xbf = (__bf16*)d_ws;
        transpose_x<<<512, 256, 0, stream>>>(xinp, xbf);
        cwdense_direct<1><<<1024, 256, 0, stream>>>(W, bias, xinp, xbf, out);
    } else {
        cwdense_direct<0><<<1024, 256, 0, stream>>>(W, bias, xinp, nullptr, out);
    }
}

// Round 10
// 109.338 us; speedup vs baseline: 1.0136x; 1.0136x over previous
//
#include <hip/hip_runtime.h>

// ---- problem constants ----
#define Bb 32     // batch
#define NN 1024   // H*W = K dim = output cols per channel
#define CC 128    // channels
#define KS 64     // K step per LDS stage
#define MT 128    // m-cols per block (4 waves x 32)
#define NSTEP (NN / KS)  // 16

typedef __bf16 bf16x8 __attribute__((ext_vector_type(8)));
typedef __bf16 bf16x4 __attribute__((ext_vector_type(4)));
typedef float f32x16 __attribute__((ext_vector_type(16)));
typedef float f32x4 __attribute__((ext_vector_type(4)));
typedef unsigned short u16x8 __attribute__((ext_vector_type(8)));

// ---------------------------------------------------------------------------
// Pre-pass: inputs [B, N, C] fp32 -> xbf [C, B, N] bf16.
// ---------------------------------------------------------------------------
__global__ __launch_bounds__(256) void transpose_x(const float* __restrict__ in,
                                                   __bf16* __restrict__ xbf) {
    __shared__ float tile[64 * 132];
    const int b  = blockIdx.x >> 4;
    const int n0 = (blockIdx.x & 15) << 6;
    const int t  = threadIdx.x;

#pragma unroll
    for (int p = 0; p < 8; ++p) {
        int f     = p * 256 + t;
        int n_off = f >> 5;
        int c4    = (f & 31) << 2;
        f32x4 v = *reinterpret_cast<const f32x4*>(in + ((size_t)(b * NN + n0 + n_off) * CC + c4));
        *reinterpret_cast<f32x4*>(&tile[n_off * 132 + c4]) = v;
    }
    __syncthreads();

    const int c = t >> 1, half = t & 1;
    const size_t obase = ((size_t)c * Bb + b) * NN + n0;
#pragma unroll
    for (int q = 0; q < 4; ++q) {
        int nb = half * 32 + q * 8;
        bf16x8 o;
#pragma unroll
        for (int j = 0; j < 8; ++j) o[j] = (__bf16)tile[(nb + j) * 132 + c];
        *reinterpret_cast<bf16x8*>(xbf + obase + nb) = o;
    }
}

// ---------------------------------------------------------------------------
// Main GEMM — R1 loop (simple 2-barrier schedule; every pipelined variant
// regressed) + H5 fix: nt W loads, epilogue writes block-private LINEAR f32
// partials (full 64-B lines, no inter-block line sharing -> no RFO/partial-
// evict write amplification). Proven 109.5us in R8.
// ---------------------------------------------------------------------------
__global__ __launch_bounds__(256) void cwdense_part(const float* __restrict__ W,
                                                    const float* __restrict__ bias,
                                                    const __bf16* __restrict__ xbf,
                                                    float* __restrict__ part) {
    __shared__ __bf16 wlds[MT * 64];  // 16 KB, row = 64 bf16 = 128 B

    const int x     = blockIdx.x;
    const int xcd   = x & 7;
    const int i     = x >> 3;
    const int c     = xcd * 16 + (i & 15);
    const int mtile = i >> 4;
    const int m0    = mtile * MT;

    const int t    = threadIdx.x;
    const int w    = t >> 6;
    const int lane = t & 63;
    const int lm   = lane & 31;
    const int lh   = lane >> 5;
    const int m_loc = w * 32 + lm;

    const float* wpanel = W + (size_t)c * NN * NN + m0;
    const __bf16* xrow  = xbf + (size_t)(c * Bb + lm) * NN;

    const int mq  = t & 31;
    const int kq2 = t >> 5;

    f32x16 acc;
#pragma unroll
    for (int r = 0; r < 16; ++r) acc[r] = 0.0f;

    for (int step = 0; step < NSTEP; ++step) {
        const int k0 = step * KS;

        // coalesced nt global loads: 8 x dwordx4 per thread
        f32x4 q[2][4];
#pragma unroll
        for (int qi = 0; qi < 2; ++qi)
#pragma unroll
            for (int r = 0; r < 4; ++r)
                q[qi][r] = __builtin_nontemporal_load(reinterpret_cast<const f32x4*>(
                    wpanel + (size_t)(k0 + (kq2 * 2 + qi) * 4 + r) * NN + mq * 4));

        __syncthreads();  // previous step's B-frag reads done before overwrite

        // in-register 4x4 transpose -> bf16 -> swizzled LDS [m][kk]
#pragma unroll
        for (int qi = 0; qi < 2; ++qi) {
            const int kkbase = (kq2 * 2 + qi) * 4;
#pragma unroll
            for (int j = 0; j < 4; ++j) {
                const int m = mq * 4 + j;
                bf16x4 o;
#pragma unroll
                for (int r = 0; r < 4; ++r) o[r] = (__bf16)q[qi][r][j];
                const int slot = (kkbase >> 3) ^ (m & 7) ^ ((m >> 3) & 7);
                *reinterpret_cast<bf16x4*>(&wlds[m * 64 + slot * 8 + (kkbase & 7)]) = o;
            }
        }
        __syncthreads();

        // 4 MFMAs covering KS=64
#pragma unroll
        for (int mi = 0; mi < 4; ++mi) {
            const int kk = mi * 16 + lh * 8;
            bf16x8 a = *reinterpret_cast<const bf16x8*>(xrow + k0 + kk);
            const int slot = (kk >> 3) ^ (m_loc & 7) ^ ((m_loc >> 3) & 7);
            bf16x8 bfrag = *reinterpret_cast<const bf16x8*>(&wlds[m_loc * 64 + slot * 8]);
            acc = __builtin_amdgcn_mfma_f32_32x32x16_bf16(a, bfrag, acc, 0, 0, 0);
        }
    }

    // epilogue: bias + relu -> part[c][b][m], block-private linear full lines
    const int m  = m0 + m_loc;
    const float bv = bias[(size_t)c * NN + m];
    float* pc = part + (size_t)c * Bb * NN;
#pragma unroll
    for (int r = 0; r < 16; ++r) {
        const int brow = (r & 3) + 8 * (r >> 2) + 4 * lh;
        float v = acc[r] + bv;
        v = v > 0.0f ? v : 0.0f;
        pc[(size_t)brow * NN + m] = v;
    }
}

// ---------------------------------------------------------------------------
// Permute pass: part[c][b][m] -> out[b][m][co], co = 127 - c. LDS-transposed
// so reads are c-major 256-B runs and writes are full f32x4 lines.
// Grid 512 = b(32) x m-tile(16 of 64).
// ---------------------------------------------------------------------------
__global__ __launch_bounds__(256) void permute_out(const float* __restrict__ part,
                                                   float* __restrict__ out) {
    __shared__ float st[CC * 65];  // [c][mm], pad 65
    const int b  = blockIdx.x >> 4;
    const int m0 = (blockIdx.x & 15) * 64;
    const int t  = threadIdx.x;

    {
        const int mm = t & 63, cr = t >> 6;
#pragma unroll 4
        for (int j = 0; j < 32; ++j) {
            const int c = cr * 32 + j;
            st[c * 65 + mm] = part[((size_t)c * Bb + b) * NN + m0 + mm];
        }
    }
    __syncthreads();
    {
        const int co4 = (t & 31) * 4, mr = t >> 5;
#pragma unroll
        for (int jj = 0; jj < 8; ++jj) {
            const int mloc = mr + 8 * jj;
            f32x4 v;
#pragma unroll
            for (int i = 0; i < 4; ++i)
                v[i] = st[(CC - 1 - co4 - i) * 65 + mloc];
            __builtin_nontemporal_store(v, reinterpret_cast<f32x4*>(
                out + ((size_t)b * NN + m0 + mloc) * CC + co4));
        }
    }
}

// ---------------------------------------------------------------------------
// Fallback (ws too small): direct-out kernel.
// ---------------------------------------------------------------------------
template <int USE_XBF>
__global__ __launch_bounds__(256) void cwdense_direct(const float* __restrict__ W,
                                                      const float* __restrict__ bias,
                                                      const float* __restrict__ xin,
                                                      const __bf16* __restrict__ xbf,
                                                      float* __restrict__ out) {
    __shared__ __bf16 wlds[MT * 64];
    const int x = blockIdx.x, xcd = x & 7, i = x >> 3;
    const int c = xcd * 16 + (i & 15), mtile = i >> 4, m0 = mtile * MT;
    const int t = threadIdx.x, w = t >> 6, lane = t & 63;
    const int lm = lane & 31, lh = lane >> 5, m_loc = w * 32 + lm;
    const float* wpanel = W + (size_t)c * NN * NN + m0;
    const int mq = t & 31, kq2 = t >> 5;

    f32x16 acc;
#pragma unroll
    for (int r = 0; r < 16; ++r) acc[r] = 0.0f;

    for (int step = 0; step < NSTEP; ++step) {
        const int k0 = step * KS;
        f32x4 q[2][4];
#pragma unroll
        for (int qi = 0; qi < 2; ++qi)
#pragma unroll
            for (int r = 0; r < 4; ++r)
                q[qi][r] = *reinterpret_cast<const f32x4*>(
                    wpanel + (size_t)(k0 + (kq2 * 2 + qi) * 4 + r) * NN + mq * 4);
        __syncthreads();
#pragma unroll
        for (int qi = 0; qi < 2; ++qi) {
            const int kkbase = (kq2 * 2 + qi) * 4;
#pragma unroll
            for (int j = 0; j < 4; ++j) {
                const int m = mq * 4 + j;
                bf16x4 o;
#pragma unroll
                for (int r = 0; r < 4; ++r) o[r] = (__bf16)q[qi][r][j];
                const int slot = (kkbase >> 3) ^ (m & 7) ^ ((m >> 3) & 7);
                *reinterpret_cast<bf16x4*>(&wlds[m * 64 + slot * 8 + (kkbase & 7)]) = o;
            }
        }
        __syncthreads();
#pragma unroll
        for (int mi = 0; mi < 4; ++mi) {
            const int kk = mi * 16 + lh * 8;
            bf16x8 a;
            if (USE_XBF) {
                a = *reinterpret_cast<const bf16x8*>(xbf + ((size_t)(c * Bb + lm) * NN + k0 + kk));
            } else {
                u16x8 tmp;
#pragma unroll
                for (int e = 0; e < 8; ++e) {
                    float f = xin[((size_t)lm * NN + (k0 + kk + e)) * CC + c];
                    unsigned u = __builtin_bit_cast(unsigned, f);
                    u = (u + 0x7FFFu + ((u >> 16) & 1u)) >> 16;
                    tmp[e] = (unsigned short)u;
                }
                a = __builtin_bit_cast(bf16x8, tmp);
            }
            const int slot = (kk >> 3) ^ (m_loc & 7) ^ ((m_loc >> 3) & 7);
            bf16x8 bfrag = *reinterpret_cast<const bf16x8*>(&wlds[m_loc * 64 + slot * 8]);
            acc = __builtin_amdgcn_mfma_f32_32x32x16_bf16(a, bfrag, acc, 0, 0, 0);
        }
    }
    const int m = m0 + m_loc;
    const float bv = bias[(size_t)c * NN + m];
    const int co = (CC - 1) - c;
#pragma unroll
    for (int r = 0; r < 16; ++r) {
        const int brow = (r & 3) + 8 * (r >> 2) + 4 * lh;
        float v = acc[r] + bv;
        v = v > 0.0f ? v : 0.0f;
        out[(size_t)brow * (NN * CC) + (size_t)m * CC + co] = v;
    }
}

extern "C" void kernel_launch(void* const* d_in, const int* in_sizes, int n_in,
                              void* d_out, int out_size, void* d_ws, size_t ws_size,
                              hipStream_t stream) {
    const float* xinp = (const float*)d_in[0];
    const float* W    = (const float*)d_in[1];
    const float* bias = (const float*)d_in[2];
    float* out        = (float*)d_out;

    const size_t part_bytes = (size_t)CC * Bb * NN * sizeof(float);   // 16 MB
    const size_t xbf_bytes  = (size_t)CC * Bb * NN * sizeof(__bf16);  // 8 MB

    if (ws_size >= part_bytes + xbf_bytes) {
        float*  part = (float*)d_ws;
        __bf16* xbf  = (__bf16*)((char*)d_ws + part_bytes);
        transpose_x<<<512, 256, 0, stream>>>(xinp, xbf);
        cwdense_part<<<1024, 256, 0, stream>>>(W, bias, xbf, part);
        permute_out<<<512, 256, 0, stream>>>(part, out);
    } else if (ws_size >= xbf_bytes) {
        __bf16* xbf = (__bf16*)d_ws;
        transpose_x<<<512, 256, 0, stream>>>(xinp, xbf);
        cwdense_direct<1><<<1024, 256, 0, stream>>>(W, bias, xinp, xbf, out);
    } else {
        cwdense_direct<0><<<1024, 256, 0, stream>>>(W, bias, xinp, nullptr, out);
    }
}